// Round 4
// baseline (964.005 us; speedup 1.0000x reference)
//
#include <hip/hip_runtime.h>

// ---------------------------------------------------------------------------
// HierarchicalMemoryCompressor: B=4, S=4096, H=2048, T=B*S=16384
// Device tensors are FP32 (per reference dtypes). Compute via bf16 MFMA with
// fp32 accumulate; selector uses hi/lo split on both operands for argmax
// fidelity. Intermediates bf16; output fp32.
// ---------------------------------------------------------------------------

typedef __bf16 bf16x8 __attribute__((ext_vector_type(8)));
typedef float  f32x4  __attribute__((ext_vector_type(4)));

#define LDW 72  // LDS row stride in ushorts: 64 data + 8 pad (144B)

__device__ __forceinline__ float bf2f(unsigned short u) {
  union { unsigned u; float f; } v; v.u = ((unsigned)u) << 16;
  return v.f;
}
__device__ __forceinline__ unsigned short f2bf(float f) {
  union { float f; unsigned u; } v; v.f = f;
  unsigned r = v.u + 0x7fffu + ((v.u >> 16) & 1u);   // RNE
  return (unsigned short)(r >> 16);
}
__device__ __forceinline__ float scrub(float v) {
  return (v == v && fabsf(v) < 1e30f) ? v : 0.f;     // NaN/Inf -> 0 (diagnostic)
}

// ---------------------------------------------------------------------------
// C[M,N] = A[M,K] @ B[K,N] + bias.  B pre-transposed+bf16 as BT[N,K].
// A is fp32 (AFP32=1, converted in staging) or bf16 (AFP32=0, intermediates).
// 128x128 tile, BK=64, 256 threads = 4 waves (2x2 of 64x64).
// MODE 0: bf16 store (intermediate). MODE 2: fp32 store where sel[row]==SELV.
// ---------------------------------------------------------------------------
template<int MODE, int SELV, int AFP32>
__global__ __launch_bounds__(256) void gemm_bt(
    const void* __restrict__ Ap, const unsigned short* __restrict__ BT,
    const float* __restrict__ bias, void* __restrict__ outp,
    const int* __restrict__ sel, int N, int K)
{
  __shared__ __align__(16) unsigned short As[128 * LDW];
  __shared__ __align__(16) unsigned short Bs[128 * LDW];
  const int tid  = threadIdx.x;
  const int lane = tid & 63;
  const int w    = tid >> 6;
  const int wr   = w >> 1, wc = w & 1;
  const int bm0  = blockIdx.y * 128;
  const int bn0  = blockIdx.x * 128;

  f32x4 acc[4][4] = {};

  for (int k0 = 0; k0 < K; k0 += 64) {
    uint4 rb[4];
    union { uint4 v; unsigned short us[8]; } ua[4];
#pragma unroll
    for (int i = 0; i < 4; ++i) {
      const int s = i * 256 + tid;           // 0..1023
      const int m = s >> 3, c = s & 7;       // row, 8-elt chunk
      rb[i] = *(const uint4*)(BT + (size_t)(bn0 + m) * K + k0 + c * 8);
      if (AFP32) {
        const float* arow = (const float*)Ap + (size_t)(bm0 + m) * K + k0 + c * 8;
        float4 a0 = *(const float4*)(arow);
        float4 a1 = *(const float4*)(arow + 4);
        ua[i].us[0] = f2bf(a0.x); ua[i].us[1] = f2bf(a0.y);
        ua[i].us[2] = f2bf(a0.z); ua[i].us[3] = f2bf(a0.w);
        ua[i].us[4] = f2bf(a1.x); ua[i].us[5] = f2bf(a1.y);
        ua[i].us[6] = f2bf(a1.z); ua[i].us[7] = f2bf(a1.w);
      } else {
        ua[i].v = *(const uint4*)((const unsigned short*)Ap +
                                  (size_t)(bm0 + m) * K + k0 + c * 8);
      }
    }
#pragma unroll
    for (int i = 0; i < 4; ++i) {
      const int s = i * 256 + tid;
      const int m = s >> 3, c = s & 7;
      *(uint4*)&As[m * LDW + c * 8] = ua[i].v;
      *(uint4*)&Bs[m * LDW + c * 8] = rb[i];
    }
    __syncthreads();
#pragma unroll
    for (int kk = 0; kk < 2; ++kk) {
      const int c = kk * 4 + (lane >> 4);    // 16B chunk in BK window
      bf16x8 af[4], bfr[4];
#pragma unroll
      for (int t = 0; t < 4; ++t) {
        const int m = wr * 64 + t * 16 + (lane & 15);
        const int n = wc * 64 + t * 16 + (lane & 15);
        af[t]  = *(const bf16x8*)&As[m * LDW + c * 8];
        bfr[t] = *(const bf16x8*)&Bs[n * LDW + c * 8];
      }
#pragma unroll
      for (int mt = 0; mt < 4; ++mt)
#pragma unroll
        for (int nt = 0; nt < 4; ++nt)
          acc[mt][nt] = __builtin_amdgcn_mfma_f32_16x16x32_bf16(
              af[mt], bfr[nt], acc[mt][nt], 0, 0, 0);
    }
    __syncthreads();
  }

  // C/D frag: col = lane&15 (N), row = (lane>>4)*4 + reg (M)
  const int colb = bn0 + wc * 64 + (lane & 15);
  const int rowb = bm0 + wr * 64 + ((lane >> 4) << 2);
  float bv[4];
#pragma unroll
  for (int nt = 0; nt < 4; ++nt) bv[nt] = bias[colb + nt * 16];
#pragma unroll
  for (int mt = 0; mt < 4; ++mt) {
#pragma unroll
    for (int r = 0; r < 4; ++r) {
      const int row = rowb + mt * 16 + r;
      if (MODE == 2) { if (sel[row] != SELV) continue; }
#pragma unroll
      for (int nt = 0; nt < 4; ++nt) {
        float v = scrub(acc[mt][nt][r] + bv[nt]);
        if (MODE == 2)
          ((float*)outp)[(size_t)row * N + colb + nt * 16] = v;
        else
          ((unsigned short*)outp)[(size_t)row * N + colb + nt * 16] = f2bf(v);
      }
    }
  }
}

// ---------------------------------------------------------------------------
// Selector GEMM: hmid = relu( (x .* mod) @ sel_W1 + b1 ), fp32 out.
// Double split: A = hiA+loA, W1 = hiW+loW (bf16 each); 4 MFMA terms give
// ~2^-18 relative residual — argmax-grade fidelity.
// ---------------------------------------------------------------------------
__global__ __launch_bounds__(256) void sel_gemm(
    const float* __restrict__ X, const float* __restrict__ FR,
    const float* __restrict__ IM,
    const unsigned short* __restrict__ BTH, const unsigned short* __restrict__ BTL,
    const float* __restrict__ bias, float* __restrict__ hmid)
{
  constexpr int K = 2048, N = 512;
  __shared__ __align__(16) unsigned short AsH[128 * LDW];
  __shared__ __align__(16) unsigned short AsL[128 * LDW];
  __shared__ __align__(16) unsigned short BsH[128 * LDW];
  __shared__ __align__(16) unsigned short BsL[128 * LDW];
  const int tid  = threadIdx.x;
  const int lane = tid & 63;
  const int w    = tid >> 6;
  const int wr   = w >> 1, wc = w & 1;
  const int bm0  = blockIdx.y * 128;
  const int bn0  = blockIdx.x * 128;

  f32x4 acc[4][4] = {};

  for (int k0 = 0; k0 < K; k0 += 64) {
    uint4 rbh[4], rbl[4];
    union { uint4 v; unsigned short us[8]; } hu[4], lu[4];
#pragma unroll
    for (int i = 0; i < 4; ++i) {
      const int s = i * 256 + tid;
      const int m = s >> 3, c = s & 7;
      rbh[i] = *(const uint4*)(BTH + (size_t)(bn0 + m) * K + k0 + c * 8);
      rbl[i] = *(const uint4*)(BTL + (size_t)(bn0 + m) * K + k0 + c * 8);
      const float* xrow = X + (size_t)(bm0 + m) * K + k0 + c * 8;
      float4 a0 = *(const float4*)(xrow);
      float4 a1 = *(const float4*)(xrow + 4);
      const float mod = (k0 + c * 8 < 1024) ? FR[bm0 + m] : IM[bm0 + m];
      float av[8] = {a0.x, a0.y, a0.z, a0.w, a1.x, a1.y, a1.z, a1.w};
#pragma unroll
      for (int j = 0; j < 8; ++j) {
        float a = av[j] * mod;
        unsigned short h = f2bf(a);
        hu[i].us[j] = h;
        lu[i].us[j] = f2bf(a - bf2f(h));
      }
    }
#pragma unroll
    for (int i = 0; i < 4; ++i) {
      const int s = i * 256 + tid;
      const int m = s >> 3, c = s & 7;
      *(uint4*)&AsH[m * LDW + c * 8] = hu[i].v;
      *(uint4*)&AsL[m * LDW + c * 8] = lu[i].v;
      *(uint4*)&BsH[m * LDW + c * 8] = rbh[i];
      *(uint4*)&BsL[m * LDW + c * 8] = rbl[i];
    }
    __syncthreads();
#pragma unroll
    for (int kk = 0; kk < 2; ++kk) {
      const int c = kk * 4 + (lane >> 4);
      bf16x8 ah[4], al[4], bh[4], bl[4];
#pragma unroll
      for (int t = 0; t < 4; ++t) {
        const int m = wr * 64 + t * 16 + (lane & 15);
        const int n = wc * 64 + t * 16 + (lane & 15);
        ah[t] = *(const bf16x8*)&AsH[m * LDW + c * 8];
        al[t] = *(const bf16x8*)&AsL[m * LDW + c * 8];
        bh[t] = *(const bf16x8*)&BsH[n * LDW + c * 8];
        bl[t] = *(const bf16x8*)&BsL[n * LDW + c * 8];
      }
#pragma unroll
      for (int mt = 0; mt < 4; ++mt)
#pragma unroll
        for (int nt = 0; nt < 4; ++nt) {
          acc[mt][nt] = __builtin_amdgcn_mfma_f32_16x16x32_bf16(
              ah[mt], bh[nt], acc[mt][nt], 0, 0, 0);
          acc[mt][nt] = __builtin_amdgcn_mfma_f32_16x16x32_bf16(
              al[mt], bh[nt], acc[mt][nt], 0, 0, 0);
          acc[mt][nt] = __builtin_amdgcn_mfma_f32_16x16x32_bf16(
              ah[mt], bl[nt], acc[mt][nt], 0, 0, 0);
          acc[mt][nt] = __builtin_amdgcn_mfma_f32_16x16x32_bf16(
              al[mt], bl[nt], acc[mt][nt], 0, 0, 0);
        }
    }
    __syncthreads();
  }

  const int colb = bn0 + wc * 64 + (lane & 15);
  const int rowb = bm0 + wr * 64 + ((lane >> 4) << 2);
  float bv[4];
#pragma unroll
  for (int nt = 0; nt < 4; ++nt) bv[nt] = bias[colb + nt * 16];
#pragma unroll
  for (int mt = 0; mt < 4; ++mt)
#pragma unroll
    for (int r = 0; r < 4; ++r) {
      const int row = rowb + mt * 16 + r;
#pragma unroll
      for (int nt = 0; nt < 4; ++nt)
        hmid[(size_t)row * N + colb + nt * 16] =
            fmaxf(scrub(acc[mt][nt][r] + bv[nt]), 0.f);
    }
}

// logits = hmid @ sel_W2 + b2 (double accum), argmax -> sel. One wave/token.
__global__ __launch_bounds__(256) void logits_argmax(
    const float* __restrict__ hmid, const float* __restrict__ W2,
    const float* __restrict__ B2, int* __restrict__ sel)
{
  const int lane = threadIdx.x & 63;
  const int wv   = threadIdx.x >> 6;
  const int t    = blockIdx.x * 4 + wv;
  const float* h = hmid + (size_t)t * 512;
  double s0 = 0.0, s1 = 0.0, s2 = 0.0;
#pragma unroll
  for (int j = 0; j < 8; ++j) {
    int e = j * 64 + lane;
    double hv = (double)h[e];
    s0 += hv * (double)W2[e * 3 + 0];
    s1 += hv * (double)W2[e * 3 + 1];
    s2 += hv * (double)W2[e * 3 + 2];
  }
  for (int o = 32; o > 0; o >>= 1) {
    s0 += __shfl_down(s0, o);
    s1 += __shfl_down(s1, o);
    s2 += __shfl_down(s2, o);
  }
  if (lane == 0) {
    s0 += (double)B2[0]; s1 += (double)B2[1]; s2 += (double)B2[2];
    int idx = 0; double b = s0;
    if (s1 > b) { b = s1; idx = 1; }   // strict >: first-max tie rule
    if (s2 > b) { idx = 2; }
    sel[t] = idx;
  }
}

// out = x (fp32) everywhere; expert kernels overwrite their rows after
__global__ __launch_bounds__(256) void copy_x(
    const float* __restrict__ X, float* __restrict__ OUT)
{
  const size_t i = (size_t)blockIdx.x * 256 + threadIdx.x;
  ((uint4*)OUT)[i] = ((const uint4*)X)[i];
}

// WT[n][k] = bf16(W[k][n]), W fp32
__global__ __launch_bounds__(256) void transpose_f2b(
    const float* __restrict__ W, unsigned short* __restrict__ WT, int K, int N)
{
  __shared__ float tile[32][33];
  const int tx = threadIdx.x & 31, ty = threadIdx.x >> 5;
  const int n0 = blockIdx.x * 32, k0 = blockIdx.y * 32;
#pragma unroll
  for (int r = 0; r < 4; ++r)
    tile[ty + r * 8][tx] = W[(size_t)(k0 + ty + r * 8) * N + n0 + tx];
  __syncthreads();
#pragma unroll
  for (int r = 0; r < 4; ++r)
    WT[(size_t)(n0 + ty + r * 8) * K + k0 + tx] = f2bf(tile[tx][ty + r * 8]);
}

// hi/lo split transpose for selector weights
__global__ __launch_bounds__(256) void transpose_split(
    const float* __restrict__ W, unsigned short* __restrict__ WH,
    unsigned short* __restrict__ WL, int K, int N)
{
  __shared__ float tile[32][33];
  const int tx = threadIdx.x & 31, ty = threadIdx.x >> 5;
  const int n0 = blockIdx.x * 32, k0 = blockIdx.y * 32;
#pragma unroll
  for (int r = 0; r < 4; ++r)
    tile[ty + r * 8][tx] = W[(size_t)(k0 + ty + r * 8) * N + n0 + tx];
  __syncthreads();
#pragma unroll
  for (int r = 0; r < 4; ++r) {
    float v = tile[tx][ty + r * 8];
    unsigned short h = f2bf(v);
    const size_t o = (size_t)(n0 + ty + r * 8) * K + k0 + tx;
    WH[o] = h;
    WL[o] = f2bf(v - bf2f(h));
  }
}

// ---------------------------------------------------------------------------
extern "C" void kernel_launch(void* const* d_in, const int* in_sizes, int n_in,
                              void* d_out, int out_size, void* d_ws, size_t ws_size,
                              hipStream_t stream) {
  typedef unsigned short us;
  const float* X   = (const float*)d_in[0];
  const float* FR  = (const float*)d_in[1];
  const float* IM  = (const float*)d_in[2];
  const float* W1  = (const float*)d_in[3];
  const float* B1  = (const float*)d_in[4];
  const float* W2  = (const float*)d_in[5];
  const float* B2  = (const float*)d_in[6];
  const float* C1W = (const float*)d_in[7];
  const float* C1B = (const float*)d_in[8];
  const float* F1W = (const float*)d_in[9];
  const float* F1B = (const float*)d_in[10];
  const float* D1W = (const float*)d_in[11];
  const float* D1B = (const float*)d_in[12];
  const float* C2W = (const float*)d_in[13];
  const float* C2B = (const float*)d_in[14];
  const float* F2W = (const float*)d_in[15];
  const float* F2B = (const float*)d_in[16];
  const float* D2W = (const float*)d_in[17];
  const float* D2B = (const float*)d_in[18];
  float* OUT = (float*)d_out;

  size_t off = 0;
  auto alloc = [&](size_t bytes) -> void* {
    void* p = (char*)d_ws + off;
    off += (bytes + 255) & ~(size_t)255;
    return p;
  };
  us* WT_selH = (us*)alloc(512ull * 2048 * 2);
  us* WT_selL = (us*)alloc(512ull * 2048 * 2);
  us* WT_c1   = (us*)alloc(1024ull * 2048 * 2);
  us* WT_f1   = (us*)alloc(1024ull * 1024 * 2);
  us* WT_d1   = (us*)alloc(2048ull * 1024 * 2);
  us* WT_c2   = (us*)alloc(512ull * 2048 * 2);
  us* WT_f2   = (us*)alloc(512ull * 512 * 2);
  us* WT_d2   = (us*)alloc(2048ull * 512 * 2);
  int* sel    = (int*)alloc(16384ull * 4);
  void* R1    = alloc(16384ull * 1024 * 2);  // hmid(fp32 16384x512) -> t1 -> u1
  void* R2    = alloc(16384ull * 1024 * 2);  // t2 -> u2
  if (ws_size < off) return;

  float* hmid = (float*)R1;
  us* t1 = (us*)R1;
  us* u1 = (us*)R1;
  us* t2 = (us*)R2;
  us* u2 = (us*)R2;

  const dim3 blk(256);
  transpose_split<<<dim3(16, 64), blk, 0, stream>>>(W1, WT_selH, WT_selL, 2048, 512);
  transpose_f2b<<<dim3(32, 64), blk, 0, stream>>>(C1W, WT_c1, 2048, 1024);
  transpose_f2b<<<dim3(32, 32), blk, 0, stream>>>(F1W, WT_f1, 1024, 1024);
  transpose_f2b<<<dim3(64, 32), blk, 0, stream>>>(D1W, WT_d1, 1024, 2048);
  transpose_f2b<<<dim3(16, 64), blk, 0, stream>>>(C2W, WT_c2, 2048, 512);
  transpose_f2b<<<dim3(16, 16), blk, 0, stream>>>(F2W, WT_f2, 512, 512);
  transpose_f2b<<<dim3(64, 16), blk, 0, stream>>>(D2W, WT_d2, 512, 2048);

  // selector -> sel
  sel_gemm<<<dim3(4, 128), blk, 0, stream>>>(X, FR, IM, WT_selH, WT_selL, B1, hmid);
  logits_argmax<<<dim3(4096), blk, 0, stream>>>(hmid, W2, B2, sel);

  // baseline: out = x everywhere
  copy_x<<<dim3(32768), blk, 0, stream>>>(X, OUT);

  // expert 1: 2048 -> 1024 -> 1024 -> 2048 (masked fp32 store sel==1)
  gemm_bt<0, 0, 1><<<dim3(8, 128), blk, 0, stream>>>(X,  WT_c1, C1B, t1, nullptr, 1024, 2048);
  gemm_bt<0, 0, 0><<<dim3(8, 128), blk, 0, stream>>>(t1, WT_f1, F1B, t2, nullptr, 1024, 1024);
  gemm_bt<2, 1, 0><<<dim3(16, 128), blk, 0, stream>>>(t2, WT_d1, D1B, OUT, sel, 2048, 1024);

  // expert 2: 2048 -> 512 -> 512 -> 2048 (masked fp32 store sel==2)
  gemm_bt<0, 0, 1><<<dim3(4, 128), blk, 0, stream>>>(X,  WT_c2, C2B, u1, nullptr, 512, 2048);
  gemm_bt<0, 0, 0><<<dim3(4, 128), blk, 0, stream>>>(u1, WT_f2, F2B, u2, nullptr, 512, 512);
  gemm_bt<2, 2, 0><<<dim3(16, 128), blk, 0, stream>>>(u2, WT_d2, D2B, OUT, sel, 2048, 512);
}

// Round 5
// 894.822 us; speedup vs baseline: 1.0773x; 1.0773x over previous
//
#include <hip/hip_runtime.h>

// ---------------------------------------------------------------------------
// HierarchicalMemoryCompressor: B=4, S=4096, H=2048, T=B*S=16384
// fp32 device tensors; bf16 MFMA compute, fp32 accumulate.
// Round 5: m97-style async global_load_lds staging (16B) with XOR-swizzled
// LDS (64-stride, lane-contiguous for the DMA, 2-way-max bank aliasing on
// ds_read_b128). sel_gemm drops the lo*lo term (3 MFMA terms). copy only
// sel==0 rows.
// ---------------------------------------------------------------------------

typedef __bf16 bf16x8 __attribute__((ext_vector_type(8)));
typedef float  f32x4  __attribute__((ext_vector_type(4)));

__device__ __forceinline__ float bf2f(unsigned short u) {
  union { unsigned u; float f; } v; v.u = ((unsigned)u) << 16;
  return v.f;
}
__device__ __forceinline__ unsigned short f2bf(float f) {
  union { float f; unsigned u; } v; v.f = f;
  unsigned r = v.u + 0x7fffu + ((v.u >> 16) & 1u);   // RNE
  return (unsigned short)(r >> 16);
}
__device__ __forceinline__ float scrub(float v) {
  return (v == v && fabsf(v) < 1e30f) ? v : 0.f;     // insurance + diagnostic
}
// async global->LDS, 16B/lane; LDS side is wave-uniform base + lane*16
__device__ __forceinline__ void gld_lds16(const void* g, void* l) {
  __builtin_amdgcn_global_load_lds(
      (const __attribute__((address_space(1))) void*)g,
      (__attribute__((address_space(3))) void*)l, 16, 0, 0);
}

// ---------------------------------------------------------------------------
// C[M,N] = A[M,K] @ B[K,N] + bias; B pre-transposed bf16 BT[N,K].
// 128x128 tile, BK=64, 256 thr = 4 waves (2x2 of 64x64).
// LDS slot s = m*8 + c' holds 16B chunk c = c'^(m&7) of row m (XOR swizzle;
// slots linear => DMA-compatible; fragment reads spread banks, 2-way max).
// AFP32=1: A is fp32, converted via register staging (B stays async).
// MODE 0: bf16 store. MODE 2: fp32 store where sel[row]==SELV.
// ---------------------------------------------------------------------------
template<int MODE, int SELV, int AFP32>
__global__ __launch_bounds__(256) void gemm_bt(
    const void* __restrict__ Ap, const unsigned short* __restrict__ BT,
    const float* __restrict__ bias, void* __restrict__ outp,
    const int* __restrict__ sel, int N, int K)
{
  __shared__ __align__(16) unsigned short As[128 * 64];
  __shared__ __align__(16) unsigned short Bs[128 * 64];
  const int tid  = threadIdx.x;
  const int lane = tid & 63;
  const int w    = tid >> 6;
  const int wr   = w >> 1, wc = w & 1;
  const int bm0  = blockIdx.y * 128;
  const int bn0  = blockIdx.x * 128;

  const unsigned short* gb[4];
  const unsigned short* gab[4];
  const float* gaf[4];
  unsigned short* la[4]; unsigned short* lb[4];
#pragma unroll
  for (int i = 0; i < 4; ++i) {
    const int s = i * 256 + tid, m = s >> 3, cp = s & 7, c = cp ^ (m & 7);
    gb[i] = BT + (size_t)(bn0 + m) * K + c * 8;
    lb[i] = &Bs[s * 8];
    la[i] = &As[s * 8];
    if (AFP32) gaf[i] = (const float*)Ap + (size_t)(bm0 + m) * K + c * 8;
    else       gab[i] = (const unsigned short*)Ap + (size_t)(bm0 + m) * K + c * 8;
  }

  f32x4 acc[4][4] = {};

  for (int k0 = 0; k0 < K; k0 += 64) {
#pragma unroll
    for (int i = 0; i < 4; ++i) { gld_lds16(gb[i], lb[i]); gb[i] += 64; }
    if (AFP32) {
#pragma unroll
      for (int i = 0; i < 4; ++i) {
        float4 a0 = *(const float4*)gaf[i];
        float4 a1 = *(const float4*)(gaf[i] + 4);
        gaf[i] += 64;
        union { uint4 v; unsigned short us[8]; } u;
        u.us[0] = f2bf(a0.x); u.us[1] = f2bf(a0.y);
        u.us[2] = f2bf(a0.z); u.us[3] = f2bf(a0.w);
        u.us[4] = f2bf(a1.x); u.us[5] = f2bf(a1.y);
        u.us[6] = f2bf(a1.z); u.us[7] = f2bf(a1.w);
        *(uint4*)la[i] = u.v;
      }
    } else {
#pragma unroll
      for (int i = 0; i < 4; ++i) { gld_lds16(gab[i], la[i]); gab[i] += 64; }
    }
    __syncthreads();   // vmcnt(0)+lgkmcnt(0) drain precedes barrier
#pragma unroll
    for (int kk = 0; kk < 2; ++kk) {
      const int cc = kk * 4 + (lane >> 4);
      bf16x8 af[4], bfr[4];
#pragma unroll
      for (int t = 0; t < 4; ++t) {
        const int m = wr * 64 + t * 16 + (lane & 15);
        const int n = wc * 64 + t * 16 + (lane & 15);
        af[t]  = *(const bf16x8*)&As[(m * 8 + (cc ^ (m & 7))) * 8];
        bfr[t] = *(const bf16x8*)&Bs[(n * 8 + (cc ^ (n & 7))) * 8];
      }
#pragma unroll
      for (int mt = 0; mt < 4; ++mt)
#pragma unroll
        for (int nt = 0; nt < 4; ++nt)
          acc[mt][nt] = __builtin_amdgcn_mfma_f32_16x16x32_bf16(
              af[mt], bfr[nt], acc[mt][nt], 0, 0, 0);
    }
    __syncthreads();
  }

  // C/D frag: col = lane&15 (N), row = (lane>>4)*4 + reg (M)
  const int colb = bn0 + wc * 64 + (lane & 15);
  const int rowb = bm0 + wr * 64 + ((lane >> 4) << 2);
  float bv[4];
#pragma unroll
  for (int nt = 0; nt < 4; ++nt) bv[nt] = bias[colb + nt * 16];
#pragma unroll
  for (int mt = 0; mt < 4; ++mt) {
#pragma unroll
    for (int r = 0; r < 4; ++r) {
      const int row = rowb + mt * 16 + r;
      if (MODE == 2) { if (sel[row] != SELV) continue; }
#pragma unroll
      for (int nt = 0; nt < 4; ++nt) {
        float v = scrub(acc[mt][nt][r] + bv[nt]);
        if (MODE == 2)
          ((float*)outp)[(size_t)row * N + colb + nt * 16] = v;
        else
          ((unsigned short*)outp)[(size_t)row * N + colb + nt * 16] = f2bf(v);
      }
    }
  }
}

// ---------------------------------------------------------------------------
// Selector GEMM: hmid = relu( (x .* mod) @ sel_W1 + b1 ), fp32 out.
// A = hiA+loA (inline from fp32), W1 = hiW+loW (precomputed); 3 MFMA terms
// (lo*lo ~2^-18 rel, below fp32 accumulation noise). B tiles async-staged.
// ---------------------------------------------------------------------------
__global__ __launch_bounds__(256) void sel_gemm(
    const float* __restrict__ X, const float* __restrict__ FR,
    const float* __restrict__ IM,
    const unsigned short* __restrict__ BTH, const unsigned short* __restrict__ BTL,
    const float* __restrict__ bias, float* __restrict__ hmid)
{
  constexpr int K = 2048, N = 512;
  __shared__ __align__(16) unsigned short AsH[128 * 64];
  __shared__ __align__(16) unsigned short AsL[128 * 64];
  __shared__ __align__(16) unsigned short BsH[128 * 64];
  __shared__ __align__(16) unsigned short BsL[128 * 64];
  const int tid  = threadIdx.x;
  const int lane = tid & 63;
  const int w    = tid >> 6;
  const int wr   = w >> 1, wc = w & 1;
  const int bm0  = blockIdx.y * 128;
  const int bn0  = blockIdx.x * 128;

  const unsigned short* gbh[4]; const unsigned short* gbl[4];
  const float* gx[4];
  unsigned short* lbh[4]; unsigned short* lbl[4];
  int sOfs[4]; float mod[4];
#pragma unroll
  for (int i = 0; i < 4; ++i) {
    const int s = i * 256 + tid, m = s >> 3, cp = s & 7, c = cp ^ (m & 7);
    gbh[i] = BTH + (size_t)(bn0 + m) * K + c * 8;
    gbl[i] = BTL + (size_t)(bn0 + m) * K + c * 8;
    lbh[i] = &BsH[s * 8];
    lbl[i] = &BsL[s * 8];
    gx[i]  = X + (size_t)(bm0 + m) * K + c * 8;
    sOfs[i] = s * 8;
    // column block of this slot: chunk c covers k-cols [c*8, c*8+8) of window
    mod[i] = 0.f; // set per-iteration (depends on k0 + c*8 vs 1024)
  }

  f32x4 acc[4][4] = {};

  for (int k0 = 0; k0 < K; k0 += 64) {
#pragma unroll
    for (int i = 0; i < 4; ++i) {
      gld_lds16(gbh[i], lbh[i]); gbh[i] += 64;
      gld_lds16(gbl[i], lbl[i]); gbl[i] += 64;
    }
#pragma unroll
    for (int i = 0; i < 4; ++i) {
      const int s = i * 256 + tid, m = s >> 3, cp = s & 7, c = cp ^ (m & 7);
      const float md = (k0 + c * 8 < 1024) ? FR[bm0 + m] : IM[bm0 + m];
      float4 a0 = *(const float4*)gx[i];
      float4 a1 = *(const float4*)(gx[i] + 4);
      gx[i] += 64;
      float av[8] = {a0.x, a0.y, a0.z, a0.w, a1.x, a1.y, a1.z, a1.w};
      union { uint4 v; unsigned short us[8]; } hu, lu;
#pragma unroll
      for (int j = 0; j < 8; ++j) {
        float a = av[j] * md;
        unsigned short h = f2bf(a);
        hu.us[j] = h;
        lu.us[j] = f2bf(a - bf2f(h));
      }
      *(uint4*)&AsH[sOfs[i]] = hu.v;
      *(uint4*)&AsL[sOfs[i]] = lu.v;
    }
    __syncthreads();
#pragma unroll
    for (int kk = 0; kk < 2; ++kk) {
      const int cc = kk * 4 + (lane >> 4);
      bf16x8 ah[4], al[4], bh[4], bl[4];
#pragma unroll
      for (int t = 0; t < 4; ++t) {
        const int m = wr * 64 + t * 16 + (lane & 15);
        const int n = wc * 64 + t * 16 + (lane & 15);
        const int ai = (m * 8 + (cc ^ (m & 7))) * 8;
        const int bi = (n * 8 + (cc ^ (n & 7))) * 8;
        ah[t] = *(const bf16x8*)&AsH[ai];
        al[t] = *(const bf16x8*)&AsL[ai];
        bh[t] = *(const bf16x8*)&BsH[bi];
        bl[t] = *(const bf16x8*)&BsL[bi];
      }
#pragma unroll
      for (int mt = 0; mt < 4; ++mt)
#pragma unroll
        for (int nt = 0; nt < 4; ++nt) {
          acc[mt][nt] = __builtin_amdgcn_mfma_f32_16x16x32_bf16(
              ah[mt], bh[nt], acc[mt][nt], 0, 0, 0);
          acc[mt][nt] = __builtin_amdgcn_mfma_f32_16x16x32_bf16(
              al[mt], bh[nt], acc[mt][nt], 0, 0, 0);
          acc[mt][nt] = __builtin_amdgcn_mfma_f32_16x16x32_bf16(
              ah[mt], bl[nt], acc[mt][nt], 0, 0, 0);
        }
    }
    __syncthreads();
  }

  const int colb = bn0 + wc * 64 + (lane & 15);
  const int rowb = bm0 + wr * 64 + ((lane >> 4) << 2);
  float bv[4];
#pragma unroll
  for (int nt = 0; nt < 4; ++nt) bv[nt] = bias[colb + nt * 16];
#pragma unroll
  for (int mt = 0; mt < 4; ++mt)
#pragma unroll
    for (int r = 0; r < 4; ++r) {
      const int row = rowb + mt * 16 + r;
#pragma unroll
      for (int nt = 0; nt < 4; ++nt)
        hmid[(size_t)row * N + colb + nt * 16] =
            fmaxf(scrub(acc[mt][nt][r] + bv[nt]), 0.f);
    }
}

// logits = hmid @ sel_W2 + b2 (double accum), argmax -> sel. One wave/token.
__global__ __launch_bounds__(256) void logits_argmax(
    const float* __restrict__ hmid, const float* __restrict__ W2,
    const float* __restrict__ B2, int* __restrict__ sel)
{
  const int lane = threadIdx.x & 63;
  const int wv   = threadIdx.x >> 6;
  const int t    = blockIdx.x * 4 + wv;
  const float* h = hmid + (size_t)t * 512;
  double s0 = 0.0, s1 = 0.0, s2 = 0.0;
#pragma unroll
  for (int j = 0; j < 8; ++j) {
    int e = j * 64 + lane;
    double hv = (double)h[e];
    s0 += hv * (double)W2[e * 3 + 0];
    s1 += hv * (double)W2[e * 3 + 1];
    s2 += hv * (double)W2[e * 3 + 2];
  }
  for (int o = 32; o > 0; o >>= 1) {
    s0 += __shfl_down(s0, o);
    s1 += __shfl_down(s1, o);
    s2 += __shfl_down(s2, o);
  }
  if (lane == 0) {
    s0 += (double)B2[0]; s1 += (double)B2[1]; s2 += (double)B2[2];
    int idx = 0; double b = s0;
    if (s1 > b) { b = s1; idx = 1; }   // strict >: first-max tie rule
    if (s2 > b) { idx = 2; }
    sel[t] = idx;
  }
}

// out[t,:] = x[t,:] only where sel==0 (experts store their own rows)
__global__ __launch_bounds__(256) void pass0(
    const float* __restrict__ X, const int* __restrict__ sel,
    float* __restrict__ OUT)
{
  const int t = blockIdx.x;
  if (sel[t] != 0) return;
  const uint4* src = (const uint4*)(X + (size_t)t * 2048);
  uint4* dst = (uint4*)(OUT + (size_t)t * 2048);
  dst[threadIdx.x]       = src[threadIdx.x];
  dst[threadIdx.x + 256] = src[threadIdx.x + 256];
}

// WT[n][k] = bf16(W[k][n]), W fp32
__global__ __launch_bounds__(256) void transpose_f2b(
    const float* __restrict__ W, unsigned short* __restrict__ WT, int K, int N)
{
  __shared__ float tile[32][33];
  const int tx = threadIdx.x & 31, ty = threadIdx.x >> 5;
  const int n0 = blockIdx.x * 32, k0 = blockIdx.y * 32;
#pragma unroll
  for (int r = 0; r < 4; ++r)
    tile[ty + r * 8][tx] = W[(size_t)(k0 + ty + r * 8) * N + n0 + tx];
  __syncthreads();
#pragma unroll
  for (int r = 0; r < 4; ++r)
    WT[(size_t)(n0 + ty + r * 8) * K + k0 + tx] = f2bf(tile[tx][ty + r * 8]);
}

// hi/lo split transpose for selector weights
__global__ __launch_bounds__(256) void transpose_split(
    const float* __restrict__ W, unsigned short* __restrict__ WH,
    unsigned short* __restrict__ WL, int K, int N)
{
  __shared__ float tile[32][33];
  const int tx = threadIdx.x & 31, ty = threadIdx.x >> 5;
  const int n0 = blockIdx.x * 32, k0 = blockIdx.y * 32;
#pragma unroll
  for (int r = 0; r < 4; ++r)
    tile[ty + r * 8][tx] = W[(size_t)(k0 + ty + r * 8) * N + n0 + tx];
  __syncthreads();
#pragma unroll
  for (int r = 0; r < 4; ++r) {
    float v = tile[tx][ty + r * 8];
    unsigned short h = f2bf(v);
    const size_t o = (size_t)(n0 + ty + r * 8) * K + k0 + tx;
    WH[o] = h;
    WL[o] = f2bf(v - bf2f(h));
  }
}

// ---------------------------------------------------------------------------
extern "C" void kernel_launch(void* const* d_in, const int* in_sizes, int n_in,
                              void* d_out, int out_size, void* d_ws, size_t ws_size,
                              hipStream_t stream) {
  typedef unsigned short us;
  const float* X   = (const float*)d_in[0];
  const float* FR  = (const float*)d_in[1];
  const float* IM  = (const float*)d_in[2];
  const float* W1  = (const float*)d_in[3];
  const float* B1  = (const float*)d_in[4];
  const float* W2  = (const float*)d_in[5];
  const float* B2  = (const float*)d_in[6];
  const float* C1W = (const float*)d_in[7];
  const float* C1B = (const float*)d_in[8];
  const float* F1W = (const float*)d_in[9];
  const float* F1B = (const float*)d_in[10];
  const float* D1W = (const float*)d_in[11];
  const float* D1B = (const float*)d_in[12];
  const float* C2W = (const float*)d_in[13];
  const float* C2B = (const float*)d_in[14];
  const float* F2W = (const float*)d_in[15];
  const float* F2B = (const float*)d_in[16];
  const float* D2W = (const float*)d_in[17];
  const float* D2B = (const float*)d_in[18];
  float* OUT = (float*)d_out;

  size_t off = 0;
  auto alloc = [&](size_t bytes) -> void* {
    void* p = (char*)d_ws + off;
    off += (bytes + 255) & ~(size_t)255;
    return p;
  };
  us* WT_selH = (us*)alloc(512ull * 2048 * 2);
  us* WT_selL = (us*)alloc(512ull * 2048 * 2);
  us* WT_c1   = (us*)alloc(1024ull * 2048 * 2);
  us* WT_f1   = (us*)alloc(1024ull * 1024 * 2);
  us* WT_d1   = (us*)alloc(2048ull * 1024 * 2);
  us* WT_c2   = (us*)alloc(512ull * 2048 * 2);
  us* WT_f2   = (us*)alloc(512ull * 512 * 2);
  us* WT_d2   = (us*)alloc(2048ull * 512 * 2);
  int* sel    = (int*)alloc(16384ull * 4);
  void* R1    = alloc(16384ull * 1024 * 2);  // hmid(fp32 16384x512) -> t1 -> u1
  void* R2    = alloc(16384ull * 1024 * 2);  // t2 -> u2
  if (ws_size < off) return;

  float* hmid = (float*)R1;
  us* t1 = (us*)R1;
  us* u1 = (us*)R1;
  us* t2 = (us*)R2;
  us* u2 = (us*)R2;

  const dim3 blk(256);
  transpose_split<<<dim3(16, 64), blk, 0, stream>>>(W1, WT_selH, WT_selL, 2048, 512);
  transpose_f2b<<<dim3(32, 64), blk, 0, stream>>>(C1W, WT_c1, 2048, 1024);
  transpose_f2b<<<dim3(32, 32), blk, 0, stream>>>(F1W, WT_f1, 1024, 1024);
  transpose_f2b<<<dim3(64, 32), blk, 0, stream>>>(D1W, WT_d1, 1024, 2048);
  transpose_f2b<<<dim3(16, 64), blk, 0, stream>>>(C2W, WT_c2, 2048, 512);
  transpose_f2b<<<dim3(16, 16), blk, 0, stream>>>(F2W, WT_f2, 512, 512);
  transpose_f2b<<<dim3(64, 16), blk, 0, stream>>>(D2W, WT_d2, 512, 2048);

  // selector -> sel
  sel_gemm<<<dim3(4, 128), blk, 0, stream>>>(X, FR, IM, WT_selH, WT_selL, B1, hmid);
  logits_argmax<<<dim3(4096), blk, 0, stream>>>(hmid, W2, B2, sel);

  // sel==0 rows: out = x
  pass0<<<dim3(16384), blk, 0, stream>>>(X, sel, OUT);

  // expert 1: 2048 -> 1024 -> 1024 -> 2048 (masked fp32 store sel==1)
  gemm_bt<0, 0, 1><<<dim3(8, 128), blk, 0, stream>>>(X,  WT_c1, C1B, t1, nullptr, 1024, 2048);
  gemm_bt<0, 0, 0><<<dim3(8, 128), blk, 0, stream>>>(t1, WT_f1, F1B, t2, nullptr, 1024, 1024);
  gemm_bt<2, 1, 0><<<dim3(16, 128), blk, 0, stream>>>(t2, WT_d1, D1B, OUT, sel, 2048, 1024);

  // expert 2: 2048 -> 512 -> 512 -> 2048 (masked fp32 store sel==2)
  gemm_bt<0, 0, 1><<<dim3(4, 128), blk, 0, stream>>>(X,  WT_c2, C2B, u1, nullptr, 512, 2048);
  gemm_bt<0, 0, 0><<<dim3(4, 128), blk, 0, stream>>>(u1, WT_f2, F2B, u2, nullptr, 512, 512);
  gemm_bt<2, 2, 0><<<dim3(16, 128), blk, 0, stream>>>(u2, WT_d2, D2B, OUT, sel, 2048, 512);
}

// Round 6
// 654.341 us; speedup vs baseline: 1.4732x; 1.3675x over previous
//
#include <hip/hip_runtime.h>

// ---------------------------------------------------------------------------
// HierarchicalMemoryCompressor: B=4, S=4096, H=2048, T=B*S=16384
// fp32 tensors; bf16 MFMA, fp32 accumulate.
// Round 6: sparse expert routing. Compact token indices per class (atomics),
// expert chains run only on compacted rows (device-count early-exit blocks,
// fixed worst-case grids), c1/c2 gather A rows via idx (fp32->bf16 in regs),
// d1/d2 scatter fp32 rows to OUT via idx (no sel test).
// ---------------------------------------------------------------------------

typedef __bf16 bf16x8 __attribute__((ext_vector_type(8)));
typedef float  f32x4  __attribute__((ext_vector_type(4)));
typedef unsigned short us;

__device__ __forceinline__ float bf2f(us u) {
  union { unsigned u; float f; } v; v.u = ((unsigned)u) << 16;
  return v.f;
}
__device__ __forceinline__ us f2bf(float f) {
  union { float f; unsigned u; } v; v.f = f;
  unsigned r = v.u + 0x7fffu + ((v.u >> 16) & 1u);   // RNE
  return (us)(r >> 16);
}
__device__ __forceinline__ float scrub(float v) {
  return (v == v && fabsf(v) < 1e30f) ? v : 0.f;     // insurance
}
__device__ __forceinline__ void gld_lds16(const void* g, void* l) {
  __builtin_amdgcn_global_load_lds(
      (const __attribute__((address_space(1))) void*)g,
      (__attribute__((address_space(3))) void*)l, 16, 0, 0);
}

// ---------------------------------------------------------------------------
// C[M,N] = A[M,K] @ B[K,N] + bias; B pre-transposed bf16 BT[N,K].
// 128x128 tile, BK=64, 256 thr = 4 waves. XOR-swizzled LDS (slot-linear for
// async DMA, 2-way max bank aliasing on ds_read_b128).
// AIDX=0: A bf16 linear (async DMA). AIDX=1: A fp32, rows gathered via aidx
// (register staging with fp32->bf16 convert).
// MODE 0: bf16 linear store. MODE 3: fp32 scatter store via oidx, row<cnt.
// cntp: device count for this class; blocks past padded M exit.
// ---------------------------------------------------------------------------
template<int MODE, int AIDX>
__global__ __launch_bounds__(256) void gemm_bt(
    const void* __restrict__ Ap, const us* __restrict__ BT,
    const float* __restrict__ bias, void* __restrict__ outp,
    const int* __restrict__ aidx, const int* __restrict__ oidx,
    const int* __restrict__ cntp, int N, int K)
{
  const int cnt = cntp[0];
  const int Mp  = (cnt + 127) & ~127;
  const int bm0 = blockIdx.y * 128;
  if (bm0 >= Mp) return;
  const int bn0 = blockIdx.x * 128;

  __shared__ __align__(16) us As[128 * 64];
  __shared__ __align__(16) us Bs[128 * 64];
  const int tid  = threadIdx.x;
  const int lane = tid & 63;
  const int w    = tid >> 6;
  const int wr   = w >> 1, wc = w & 1;

  const us* gb[4];
  const us* gab[4];
  const float* gaf[4];
  us* la[4]; us* lb[4];
#pragma unroll
  for (int i = 0; i < 4; ++i) {
    const int s = i * 256 + tid, m = s >> 3, cp = s & 7, c = cp ^ (m & 7);
    gb[i] = BT + (size_t)(bn0 + m) * K + c * 8;
    lb[i] = &Bs[s * 8];
    la[i] = &As[s * 8];
    if (AIDX) {
      const int arow = aidx[bm0 + m];           // padded region -> 0 (safe)
      gaf[i] = (const float*)Ap + (size_t)arow * K + c * 8;
    } else {
      gab[i] = (const us*)Ap + (size_t)(bm0 + m) * K + c * 8;
    }
  }

  f32x4 acc[4][4] = {};

  for (int k0 = 0; k0 < K; k0 += 64) {
#pragma unroll
    for (int i = 0; i < 4; ++i) { gld_lds16(gb[i], lb[i]); gb[i] += 64; }
    if (AIDX) {
#pragma unroll
      for (int i = 0; i < 4; ++i) {
        float4 a0 = *(const float4*)gaf[i];
        float4 a1 = *(const float4*)(gaf[i] + 4);
        gaf[i] += 64;
        union { uint4 v; us u[8]; } t;
        t.u[0] = f2bf(a0.x); t.u[1] = f2bf(a0.y);
        t.u[2] = f2bf(a0.z); t.u[3] = f2bf(a0.w);
        t.u[4] = f2bf(a1.x); t.u[5] = f2bf(a1.y);
        t.u[6] = f2bf(a1.z); t.u[7] = f2bf(a1.w);
        *(uint4*)la[i] = t.v;
      }
    } else {
#pragma unroll
      for (int i = 0; i < 4; ++i) { gld_lds16(gab[i], la[i]); gab[i] += 64; }
    }
    __syncthreads();
#pragma unroll
    for (int kk = 0; kk < 2; ++kk) {
      const int cc = kk * 4 + (lane >> 4);
      bf16x8 af[4], bfr[4];
#pragma unroll
      for (int t = 0; t < 4; ++t) {
        const int m = wr * 64 + t * 16 + (lane & 15);
        const int n = wc * 64 + t * 16 + (lane & 15);
        af[t]  = *(const bf16x8*)&As[(m * 8 + (cc ^ (m & 7))) * 8];
        bfr[t] = *(const bf16x8*)&Bs[(n * 8 + (cc ^ (n & 7))) * 8];
      }
#pragma unroll
      for (int mt = 0; mt < 4; ++mt)
#pragma unroll
        for (int nt = 0; nt < 4; ++nt)
          acc[mt][nt] = __builtin_amdgcn_mfma_f32_16x16x32_bf16(
              af[mt], bfr[nt], acc[mt][nt], 0, 0, 0);
    }
    __syncthreads();
  }

  // C/D frag: col = lane&15 (N), row = (lane>>4)*4 + reg (M)
  const int colb = bn0 + wc * 64 + (lane & 15);
  const int rowb = bm0 + wr * 64 + ((lane >> 4) << 2);
  float bv[4];
#pragma unroll
  for (int nt = 0; nt < 4; ++nt) bv[nt] = bias[colb + nt * 16];
#pragma unroll
  for (int mt = 0; mt < 4; ++mt) {
#pragma unroll
    for (int r = 0; r < 4; ++r) {
      const int row = rowb + mt * 16 + r;
      if (MODE == 3) {
        if (row >= cnt) continue;
        const size_t orow = (size_t)oidx[row];
#pragma unroll
        for (int nt = 0; nt < 4; ++nt)
          ((float*)outp)[orow * N + colb + nt * 16] =
              scrub(acc[mt][nt][r] + bv[nt]);
      } else {
#pragma unroll
        for (int nt = 0; nt < 4; ++nt)
          ((us*)outp)[(size_t)row * N + colb + nt * 16] =
              f2bf(scrub(acc[mt][nt][r] + bv[nt]));
      }
    }
  }
}

// ---------------------------------------------------------------------------
// Selector GEMM: hmid = relu( (x .* mod) @ sel_W1 + b1 ), fp32 out.
// A hi/lo split inline; W1 hi/lo precomputed; 3 MFMA terms (~2^-16 rel).
// ---------------------------------------------------------------------------
__global__ __launch_bounds__(256) void sel_gemm(
    const float* __restrict__ X, const float* __restrict__ FR,
    const float* __restrict__ IM,
    const us* __restrict__ BTH, const us* __restrict__ BTL,
    const float* __restrict__ bias, float* __restrict__ hmid)
{
  constexpr int K = 2048, N = 512;
  __shared__ __align__(16) us AsH[128 * 64];
  __shared__ __align__(16) us AsL[128 * 64];
  __shared__ __align__(16) us BsH[128 * 64];
  __shared__ __align__(16) us BsL[128 * 64];
  const int tid  = threadIdx.x;
  const int lane = tid & 63;
  const int w    = tid >> 6;
  const int wr   = w >> 1, wc = w & 1;
  const int bm0  = blockIdx.y * 128;
  const int bn0  = blockIdx.x * 128;

  const us* gbh[4]; const us* gbl[4];
  const float* gx[4];
  us* lbh[4]; us* lbl[4];
  int sOfs[4];
#pragma unroll
  for (int i = 0; i < 4; ++i) {
    const int s = i * 256 + tid, m = s >> 3, cp = s & 7, c = cp ^ (m & 7);
    gbh[i] = BTH + (size_t)(bn0 + m) * K + c * 8;
    gbl[i] = BTL + (size_t)(bn0 + m) * K + c * 8;
    lbh[i] = &BsH[s * 8];
    lbl[i] = &BsL[s * 8];
    gx[i]  = X + (size_t)(bm0 + m) * K + c * 8;
    sOfs[i] = s * 8;
  }

  f32x4 acc[4][4] = {};

  for (int k0 = 0; k0 < K; k0 += 64) {
#pragma unroll
    for (int i = 0; i < 4; ++i) {
      gld_lds16(gbh[i], lbh[i]); gbh[i] += 64;
      gld_lds16(gbl[i], lbl[i]); gbl[i] += 64;
    }
#pragma unroll
    for (int i = 0; i < 4; ++i) {
      const int s = i * 256 + tid, m = s >> 3, cp = s & 7, c = cp ^ (m & 7);
      const float md = (k0 + c * 8 < 1024) ? FR[bm0 + m] : IM[bm0 + m];
      float4 a0 = *(const float4*)gx[i];
      float4 a1 = *(const float4*)(gx[i] + 4);
      gx[i] += 64;
      float av[8] = {a0.x, a0.y, a0.z, a0.w, a1.x, a1.y, a1.z, a1.w};
      union { uint4 v; us u[8]; } hu, lu;
#pragma unroll
      for (int j = 0; j < 8; ++j) {
        float a = av[j] * md;
        us h = f2bf(a);
        hu.u[j] = h;
        lu.u[j] = f2bf(a - bf2f(h));
      }
      *(uint4*)&AsH[sOfs[i]] = hu.v;
      *(uint4*)&AsL[sOfs[i]] = lu.v;
    }
    __syncthreads();
#pragma unroll
    for (int kk = 0; kk < 2; ++kk) {
      const int cc = kk * 4 + (lane >> 4);
      bf16x8 ah[4], al[4], bh[4], bl[4];
#pragma unroll
      for (int t = 0; t < 4; ++t) {
        const int m = wr * 64 + t * 16 + (lane & 15);
        const int n = wc * 64 + t * 16 + (lane & 15);
        const int ai = (m * 8 + (cc ^ (m & 7))) * 8;
        const int bi = (n * 8 + (cc ^ (n & 7))) * 8;
        ah[t] = *(const bf16x8*)&AsH[ai];
        al[t] = *(const bf16x8*)&AsL[ai];
        bh[t] = *(const bf16x8*)&BsH[bi];
        bl[t] = *(const bf16x8*)&BsL[bi];
      }
#pragma unroll
      for (int mt = 0; mt < 4; ++mt)
#pragma unroll
        for (int nt = 0; nt < 4; ++nt) {
          acc[mt][nt] = __builtin_amdgcn_mfma_f32_16x16x32_bf16(
              ah[mt], bh[nt], acc[mt][nt], 0, 0, 0);
          acc[mt][nt] = __builtin_amdgcn_mfma_f32_16x16x32_bf16(
              al[mt], bh[nt], acc[mt][nt], 0, 0, 0);
          acc[mt][nt] = __builtin_amdgcn_mfma_f32_16x16x32_bf16(
              ah[mt], bl[nt], acc[mt][nt], 0, 0, 0);
        }
    }
    __syncthreads();
  }

  const int colb = bn0 + wc * 64 + (lane & 15);
  const int rowb = bm0 + wr * 64 + ((lane >> 4) << 2);
  float bv[4];
#pragma unroll
  for (int nt = 0; nt < 4; ++nt) bv[nt] = bias[colb + nt * 16];
#pragma unroll
  for (int mt = 0; mt < 4; ++mt)
#pragma unroll
    for (int r = 0; r < 4; ++r) {
      const int row = rowb + mt * 16 + r;
#pragma unroll
      for (int nt = 0; nt < 4; ++nt)
        hmid[(size_t)row * N + colb + nt * 16] =
            fmaxf(scrub(acc[mt][nt][r] + bv[nt]), 0.f);
    }
}

// logits = hmid @ sel_W2 + b2 (double accum), argmax -> sel. One wave/token.
__global__ __launch_bounds__(256) void logits_argmax(
    const float* __restrict__ hmid, const float* __restrict__ W2,
    const float* __restrict__ B2, int* __restrict__ sel)
{
  const int lane = threadIdx.x & 63;
  const int wv   = threadIdx.x >> 6;
  const int t    = blockIdx.x * 4 + wv;
  const float* h = hmid + (size_t)t * 512;
  double s0 = 0.0, s1 = 0.0, s2 = 0.0;
#pragma unroll
  for (int j = 0; j < 8; ++j) {
    int e = j * 64 + lane;
    double hv = (double)h[e];
    s0 += hv * (double)W2[e * 3 + 0];
    s1 += hv * (double)W2[e * 3 + 1];
    s2 += hv * (double)W2[e * 3 + 2];
  }
  for (int o = 32; o > 0; o >>= 1) {
    s0 += __shfl_down(s0, o);
    s1 += __shfl_down(s1, o);
    s2 += __shfl_down(s2, o);
  }
  if (lane == 0) {
    s0 += (double)B2[0]; s1 += (double)B2[1]; s2 += (double)B2[2];
    int idx = 0; double b = s0;
    if (s1 > b) { b = s1; idx = 1; }   // strict >: first-max tie rule
    if (s2 > b) { idx = 2; }
    sel[t] = idx;
  }
}

// Build compacted index lists per class (order-free, wave-aggregated atomics)
__global__ __launch_bounds__(256) void compact(
    const int* __restrict__ sel, int* __restrict__ cnt,
    int* __restrict__ idx1, int* __restrict__ idx2)
{
  const int t    = blockIdx.x * 256 + threadIdx.x;
  const int lane = threadIdx.x & 63;
  const int w    = threadIdx.x >> 6;
  const int s    = sel[t];
  const bool f1 = (s == 1), f2 = (s == 2);
  const unsigned long long m1 = __ballot(f1);
  const unsigned long long m2 = __ballot(f2);
  const unsigned long long lt = (1ull << lane) - 1ull;  // lane<=63: defined
  const int b1 = __popcll(m1 & lt);
  const int b2 = __popcll(m2 & lt);
  __shared__ int w1[4], w2[4], base1, base2;
  if (lane == 0) { w1[w] = __popcll(m1); w2[w] = __popcll(m2); }
  __syncthreads();
  if (threadIdx.x == 0) {
    base1 = atomicAdd(&cnt[0], w1[0] + w1[1] + w1[2] + w1[3]);
    base2 = atomicAdd(&cnt[1], w2[0] + w2[1] + w2[2] + w2[3]);
  }
  __syncthreads();
  int o1 = base1, o2 = base2;
  for (int i = 0; i < w; ++i) { o1 += w1[i]; o2 += w2[i]; }
  if (f1) idx1[o1 + b1] = t;
  if (f2) idx2[o2 + b2] = t;
}

// pad idx tails so gather rows in [cnt, Mp) read token 0 (results discarded)
__global__ __launch_bounds__(128) void pad_idx(
    const int* __restrict__ cnt, int* __restrict__ idx1, int* __restrict__ idx2)
{
  idx1[cnt[0] + threadIdx.x] = 0;
  idx2[cnt[1] + threadIdx.x] = 0;
}

// out[t,:] = x[t,:] where sel==0
__global__ __launch_bounds__(256) void pass0(
    const float* __restrict__ X, const int* __restrict__ sel,
    float* __restrict__ OUT)
{
  const int t = blockIdx.x;
  if (sel[t] != 0) return;
  const uint4* src = (const uint4*)(X + (size_t)t * 2048);
  uint4* dst = (uint4*)(OUT + (size_t)t * 2048);
  dst[threadIdx.x]       = src[threadIdx.x];
  dst[threadIdx.x + 256] = src[threadIdx.x + 256];
}

// WT[n][k] = bf16(W[k][n]), W fp32
__global__ __launch_bounds__(256) void transpose_f2b(
    const float* __restrict__ W, us* __restrict__ WT, int K, int N)
{
  __shared__ float tile[32][33];
  const int tx = threadIdx.x & 31, ty = threadIdx.x >> 5;
  const int n0 = blockIdx.x * 32, k0 = blockIdx.y * 32;
#pragma unroll
  for (int r = 0; r < 4; ++r)
    tile[ty + r * 8][tx] = W[(size_t)(k0 + ty + r * 8) * N + n0 + tx];
  __syncthreads();
#pragma unroll
  for (int r = 0; r < 4; ++r)
    WT[(size_t)(n0 + ty + r * 8) * K + k0 + tx] = f2bf(tile[tx][ty + r * 8]);
}

// hi/lo split transpose for selector weights
__global__ __launch_bounds__(256) void transpose_split(
    const float* __restrict__ W, us* __restrict__ WH, us* __restrict__ WL,
    int K, int N)
{
  __shared__ float tile[32][33];
  const int tx = threadIdx.x & 31, ty = threadIdx.x >> 5;
  const int n0 = blockIdx.x * 32, k0 = blockIdx.y * 32;
#pragma unroll
  for (int r = 0; r < 4; ++r)
    tile[ty + r * 8][tx] = W[(size_t)(k0 + ty + r * 8) * N + n0 + tx];
  __syncthreads();
#pragma unroll
  for (int r = 0; r < 4; ++r) {
    float v = tile[tx][ty + r * 8];
    us h = f2bf(v);
    const size_t o = (size_t)(n0 + ty + r * 8) * K + k0 + tx;
    WH[o] = h;
    WL[o] = f2bf(v - bf2f(h));
  }
}

// ---------------------------------------------------------------------------
extern "C" void kernel_launch(void* const* d_in, const int* in_sizes, int n_in,
                              void* d_out, int out_size, void* d_ws, size_t ws_size,
                              hipStream_t stream) {
  const float* X   = (const float*)d_in[0];
  const float* FR  = (const float*)d_in[1];
  const float* IM  = (const float*)d_in[2];
  const float* W1  = (const float*)d_in[3];
  const float* B1  = (const float*)d_in[4];
  const float* W2  = (const float*)d_in[5];
  const float* B2  = (const float*)d_in[6];
  const float* C1W = (const float*)d_in[7];
  const float* C1B = (const float*)d_in[8];
  const float* F1W = (const float*)d_in[9];
  const float* F1B = (const float*)d_in[10];
  const float* D1W = (const float*)d_in[11];
  const float* D1B = (const float*)d_in[12];
  const float* C2W = (const float*)d_in[13];
  const float* C2B = (const float*)d_in[14];
  const float* F2W = (const float*)d_in[15];
  const float* F2B = (const float*)d_in[16];
  const float* D2W = (const float*)d_in[17];
  const float* D2B = (const float*)d_in[18];
  float* OUT = (float*)d_out;

  size_t off = 0;
  auto alloc = [&](size_t bytes) -> void* {
    void* p = (char*)d_ws + off;
    off += (bytes + 255) & ~(size_t)255;
    return p;
  };
  us* WT_selH = (us*)alloc(512ull * 2048 * 2);
  us* WT_selL = (us*)alloc(512ull * 2048 * 2);
  us* WT_c1   = (us*)alloc(1024ull * 2048 * 2);
  us* WT_f1   = (us*)alloc(1024ull * 1024 * 2);
  us* WT_d1   = (us*)alloc(2048ull * 1024 * 2);
  us* WT_c2   = (us*)alloc(512ull * 2048 * 2);
  us* WT_f2   = (us*)alloc(512ull * 512 * 2);
  us* WT_d2   = (us*)alloc(2048ull * 512 * 2);
  int* sel    = (int*)alloc(16384ull * 4);
  int* cnt    = (int*)alloc(2 * 4);
  int* idx1   = (int*)alloc((16384ull + 128) * 4);
  int* idx2   = (int*)alloc((16384ull + 128) * 4);
  void* R1    = alloc(16384ull * 1024 * 2);  // hmid(fp32 16384x512) -> t1 -> u1
  void* R2    = alloc(16384ull * 1024 * 2);  // t2 -> u2
  if (ws_size < off) return;

  float* hmid = (float*)R1;
  us* t1 = (us*)R1;
  us* u1 = (us*)R1;
  us* t2 = (us*)R2;
  us* u2 = (us*)R2;

  const dim3 blk(256);
  transpose_split<<<dim3(16, 64), blk, 0, stream>>>(W1, WT_selH, WT_selL, 2048, 512);
  transpose_f2b<<<dim3(32, 64), blk, 0, stream>>>(C1W, WT_c1, 2048, 1024);
  transpose_f2b<<<dim3(32, 32), blk, 0, stream>>>(F1W, WT_f1, 1024, 1024);
  transpose_f2b<<<dim3(64, 32), blk, 0, stream>>>(D1W, WT_d1, 1024, 2048);
  transpose_f2b<<<dim3(16, 64), blk, 0, stream>>>(C2W, WT_c2, 2048, 512);
  transpose_f2b<<<dim3(16, 16), blk, 0, stream>>>(F2W, WT_f2, 512, 512);
  transpose_f2b<<<dim3(64, 16), blk, 0, stream>>>(D2W, WT_d2, 512, 2048);

  // selector -> sel -> compacted index lists
  sel_gemm<<<dim3(4, 128), blk, 0, stream>>>(X, FR, IM, WT_selH, WT_selL, B1, hmid);
  logits_argmax<<<dim3(4096), blk, 0, stream>>>(hmid, W2, B2, sel);
  hipMemsetAsync(cnt, 0, 8, stream);
  compact<<<dim3(64), blk, 0, stream>>>(sel, cnt, idx1, idx2);
  pad_idx<<<dim3(1), dim3(128), 0, stream>>>(cnt, idx1, idx2);

  // sel==0 rows: out = x
  pass0<<<dim3(16384), blk, 0, stream>>>(X, sel, OUT);

  // expert 1 (compacted): X[idx1] -> 1024 -> 1024 -> scatter 2048
  gemm_bt<0, 1><<<dim3(8, 128), blk, 0, stream>>>(X,  WT_c1, C1B, t1, idx1, nullptr, cnt + 0, 1024, 2048);
  gemm_bt<0, 0><<<dim3(8, 128), blk, 0, stream>>>(t1, WT_f1, F1B, t2, nullptr, nullptr, cnt + 0, 1024, 1024);
  gemm_bt<3, 0><<<dim3(16, 128), blk, 0, stream>>>(t2, WT_d1, D1B, OUT, nullptr, idx1, cnt + 0, 2048, 1024);

  // expert 2 (compacted): X[idx2] -> 512 -> 512 -> scatter 2048
  gemm_bt<0, 1><<<dim3(4, 128), blk, 0, stream>>>(X,  WT_c2, C2B, u1, idx2, nullptr, cnt + 1, 512, 2048);
  gemm_bt<0, 0><<<dim3(4, 128), blk, 0, stream>>>(u1, WT_f2, F2B, u2, nullptr, nullptr, cnt + 1, 512, 512);
  gemm_bt<3, 0><<<dim3(16, 128), blk, 0, stream>>>(u2, WT_d2, D2B, OUT, nullptr, idx2, cnt + 1, 2048, 512);
}